// Round 14
// baseline (138.264 us; speedup 1.0000x reference)
//
#include <hip/hip_runtime.h>
#include <math.h>

#define NOISE 1e-12f
#define WSZ 1064    // floats per staging buffer: THc(200) | F(64) | G1c(400) | G2c(400)
#define WSZ4 266

typedef float f32x2 __attribute__((ext_vector_type(2)));

__device__ __forceinline__ f32x2 mk2(float x, float y){ f32x2 r; r.x = x; r.y = y; return r; }

// packed complex multiply: returns a (x) b, 2 VOP3P instructions
__device__ __forceinline__ f32x2 cmul_pk(f32x2 a, f32x2 b) {
    f32x2 w;
    asm("v_pk_mul_f32 %0, %1, %2 op_sel:[0,0] op_sel_hi:[0,1]\n\t"
        "v_pk_fma_f32 %0, %1, %2, %0 op_sel:[1,1,0] op_sel_hi:[1,0,1] neg_lo:[0,1,0]"
        : "=&v"(w) : "v"(a), "v"(b));
    return w;
}
// packed complex FMA: p += a (x) w, 2 VOP3P instructions
__device__ __forceinline__ void cfma_pk(f32x2& p, f32x2 a, f32x2 w) {
    asm("v_pk_fma_f32 %0, %1, %2, %0 op_sel:[0,0,0] op_sel_hi:[0,1,1]\n\t"
        "v_pk_fma_f32 %0, %1, %2, %0 op_sel:[1,1,0] op_sel_hi:[1,0,1] neg_lo:[0,1,0]"
        : "+v"(p) : "v"(a), "v"(w));
}

__device__ __forceinline__ float2 cmul(float2 a, float2 b) {
    return make_float2(a.x*b.x - a.y*b.y, a.x*b.y + a.y*b.x);
}
__device__ __forceinline__ float2 cconjmul(float2 a, float2 b) {
    return make_float2(a.x*b.x + a.y*b.y, a.x*b.y - a.y*b.x);
}
__device__ __forceinline__ float2 cmulconj(float2 a, float2 b) {
    return make_float2(a.x*b.x + a.y*b.y, a.y*b.x - a.x*b.y);
}
__device__ __forceinline__ float2 cadd(float2 a, float2 b){ return make_float2(a.x+b.x, a.y+b.y); }
__device__ __forceinline__ float2 csub(float2 a, float2 b){ return make_float2(a.x-b.x, a.y-b.y); }
__device__ __forceinline__ float2 cscale(float s, float2 a){ return make_float2(s*a.x, s*a.y); }

// async global->LDS, 4 B per lane: lane l writes dst+4*l from per-lane src.
// Even/odd lane split performs the (re,im) interleave in the DMA engine.
typedef const void __attribute__((address_space(1)))* gas_t;
typedef void __attribute__((address_space(3)))* las_t;
__device__ __forceinline__ void gll4(const float* g, float* l) {
    __builtin_amdgcn_global_load_lds((gas_t)g, (las_t)l, 4, 0, 0);
}

// one wave per batch element iteration; 4 waves/block; 4 iterations -> 16 b per block
__global__ __launch_bounds__(256) void rate_kernel(
    const float* __restrict__ t1,
    const float* __restrict__ G1r, const float* __restrict__ G1i,
    const float* __restrict__ G2r, const float* __restrict__ G2i,
    const float* __restrict__ Ur,  const float* __restrict__ Ui,
    float* __restrict__ partial)
{
    __shared__ float4 lds4[4 * WSZ4];   // per-wave SINGLE staging buffer (19 KB/block)
    __shared__ float2 ent[4][4][16];    // [wave][it][entry]
    __shared__ float wsum[4];
    const int wave = threadIdx.x >> 6;
    const int lane = threadIdx.x & 63;
    const int t  = lane & 7;     // output column of phi
    const int k0 = lane >> 3;    // k-block id: lane handles k = 4*k0 + 32*j + c
    const int e8 = k0;
    const int nn = (e8 >> 1) & 1;
    const int rr = e8 & 1;
    float* W = (float*)(lds4 + wave * WSZ4);
    const float4* F4 = (const float4*)W;

    const int half  = lane & 1;     // 0 -> re stream, 1 -> im stream
    const int qh    = lane >> 1;    // complex index within a 32-pair chunk

    // LDS layout (floats): THc[0..199]=(θr,θi)x100 | F[200..263] raw tb[200..263] |
    //   G1c[264..663]=(g1r,g1i)x200 | G2c[664..1063]
    // 19 vmcnt-counted gll4 issues; no VGPRs held, no DS writes.
    #define STAGE(dst, bb) {                                                   \
        const float* tb_ = t1 + (long)(bb) * 264;                              \
        const float* ts  = tb_ + (half ? 100 : 0) + qh;                        \
        gll4(ts,       (dst));        gll4(ts + 32,  (dst) + 64);              \
        gll4(ts + 64,  (dst) + 128);                                           \
        if (lane < 8) gll4(ts + 96, (dst) + 192);                              \
        gll4(tb_ + 200 + lane, (dst) + 200);                                   \
        const float* g1 = (half ? G1i : G1r) + (long)(bb) * 200 + qh;          \
        const float* g2 = (half ? G2i : G2r) + (long)(bb) * 200 + qh;          \
        gll4(g1,        (dst)+264);   gll4(g1+32,  (dst)+328);                 \
        gll4(g1+64,     (dst)+392);   gll4(g1+96,  (dst)+456);                 \
        gll4(g1+128,    (dst)+520);   gll4(g1+160, (dst)+584);                 \
        if (lane < 16) gll4(g1+192, (dst)+648);                                \
        gll4(g2,        (dst)+664);   gll4(g2+32,  (dst)+728);                 \
        gll4(g2+64,     (dst)+792);   gll4(g2+96,  (dst)+856);                 \
        gll4(g2+128,    (dst)+920);   gll4(g2+160, (dst)+984);                 \
        if (lane < 16) gll4(g2+192, (dst)+1048);                               \
    }

    const long bbase = (long)blockIdx.x * 16 + (long)wave * 4;
    STAGE(W, bbase);   // prologue: stage b0

    const float* urb = Ur + bbase * 800;
    const float* uib = Ui + bbase * 800;
    const int uoff = 32 * k0 + t;
    #define LDU2(idx) mk2(urb[(idx)], uib[(idx)])

    // initial U prefetch for it 0, j=0 (AFTER the stage issues: vmcnt order)
    f32x2 u0 = LDU2(uoff), u1 = LDU2(uoff+8), u2 = LDU2(uoff+16), u3 = LDU2(uoff+24);

    // one j-group: 10 ds_read_b128 + 4 k's of packed complex math (40 VOP3P)
    #define JGROUP_PK(f0, U0, U1, U2, U3) {                                   \
        float4 t01 = F4[(f0)],      t23 = F4[(f0)+1];                         \
        float4 a01 = F4[66+(f0)],   a23 = F4[67+(f0)];                        \
        float4 c01 = F4[116+(f0)],  c23 = F4[117+(f0)];                       \
        float4 d01 = F4[166+(f0)],  d23 = F4[167+(f0)];                       \
        float4 e01 = F4[216+(f0)],  e23 = F4[217+(f0)];                       \
        { f32x2 Wk = cmul_pk(mk2(t01.x,t01.y), U0);                           \
          cfma_pk(p10, mk2(a01.x,a01.y), Wk); cfma_pk(p11, mk2(c01.x,c01.y), Wk); \
          cfma_pk(p20, mk2(d01.x,d01.y), Wk); cfma_pk(p21, mk2(e01.x,e01.y), Wk); } \
        { f32x2 Wk = cmul_pk(mk2(t01.z,t01.w), U1);                           \
          cfma_pk(p10, mk2(a01.z,a01.w), Wk); cfma_pk(p11, mk2(c01.z,c01.w), Wk); \
          cfma_pk(p20, mk2(d01.z,d01.w), Wk); cfma_pk(p21, mk2(e01.z,e01.w), Wk); } \
        { f32x2 Wk = cmul_pk(mk2(t23.x,t23.y), U2);                           \
          cfma_pk(p10, mk2(a23.x,a23.y), Wk); cfma_pk(p11, mk2(c23.x,c23.y), Wk); \
          cfma_pk(p20, mk2(d23.x,d23.y), Wk); cfma_pk(p21, mk2(e23.x,e23.y), Wk); } \
        { f32x2 Wk = cmul_pk(mk2(t23.z,t23.w), U3);                           \
          cfma_pk(p10, mk2(a23.z,a23.w), Wk); cfma_pk(p11, mk2(c23.z,c23.w), Wk); \
          cfma_pk(p20, mk2(d23.z,d23.w), Wk); cfma_pk(p21, mk2(e23.z,e23.w), Wk); } }

    const int idxF = lane & 15;
    const int selF = (lane >> 4) & 1;
    const int jf   = t*2 + rr;

    for (int it = 0; it < 4; ++it) {
        // staging complete: outstanding = [19 stage (older)] + [8 U (newer)]
        asm volatile("s_waitcnt vmcnt(8)" ::: "memory");
        __builtin_amdgcn_sched_barrier(0);

        // pull the 6 F-scalars into regs NOW (buffer gets overwritten mid-it)
        float fr = W[200 + selF*32 + idxF];
        float fi = W[216 + selF*32 + idxF];
        float2 f1 = make_float2(W[200 + jf], W[216 + jf]);
        float2 f2 = make_float2(W[232 + jf], W[248 + jf]);

        // phi accumulators (packed re,im): p10=phi1 n0, p11=phi1 n1, p20/p21=phi2
        f32x2 p10 = mk2(0.f,0.f), p11 = mk2(0.f,0.f);
        f32x2 p20 = mk2(0.f,0.f), p21 = mk2(0.f,0.f);

        #pragma unroll 1   // rolled: keep VGPR bounded; prefetch provides ILP
        for (int j = 0; j < 3; ++j) {
            f32x2 n0, n1, n2, n3;
            if (j < 2) {
                const int nb = uoff + 256 * (j + 1);
                n0 = LDU2(nb); n1 = LDU2(nb+8); n2 = LDU2(nb+16); n3 = LDU2(nb+24);
            } else {
                // tail strips k=96..99: idx <= 799, in-bounds for all lanes
                n0 = LDU2(768+t); n1 = LDU2(776+t); n2 = LDU2(784+t); n3 = LDU2(792+t);
            }
            JGROUP_PK(2*k0 + 16*j, u0, u1, u2, u3);
            u0 = n0; u1 = n1; u2 = n2; u3 = n3;
        }
        // tail: k = 96..99, only k0==0 lanes contribute
        if (k0 == 0) {
            JGROUP_PK(48, u0, u1, u2, u3);
        }

        // all this-buffer LDS reads complete -> restage same buffer for it+1;
        // the gll4s fly under the shuffle phase below (~800 cyc).
        if (it < 3) {
            asm volatile("s_waitcnt lgkmcnt(0)" ::: "memory");
            __builtin_amdgcn_sched_barrier(0);
            STAGE(W, bbase + it + 1);
            __builtin_amdgcn_sched_barrier(0);
            // cross-it U prefetch (AFTER stage: keeps vmcnt split [19][8])
            urb += 800; uib += 800;
            u0 = LDU2(uoff); u1 = LDU2(uoff+8); u2 = LDU2(uoff+16); u3 = LDU2(uoff+24);
            __builtin_amdgcn_sched_barrier(0);
        }

        // reduce over the 8 k-blocks (lane bits 3..5) — registers only
        float p[8] = {p10.x, p10.y, p11.x, p11.y, p20.x, p20.y, p21.x, p21.y};
        #pragma unroll
        for (int q = 0; q < 8; ++q) {
            p[q] += __shfl_xor(p[q], 8);
            p[q] += __shfl_xor(p[q], 32);
        }
        float4 ph;
        {
            float k0r = nn ? p[2] : p[0], s0r = nn ? p[0] : p[2];
            float k0i = nn ? p[3] : p[1], s0i = nn ? p[1] : p[3];
            float k1r = nn ? p[6] : p[4], s1r = nn ? p[4] : p[6];
            float k1i = nn ? p[7] : p[5], s1i = nn ? p[5] : p[7];
            ph.x = k0r + __shfl_xor(s0r, 16);
            ph.y = k0i + __shfl_xor(s0i, 16);
            ph.z = k1r + __shfl_xor(s1r, 16);
            ph.w = k1i + __shfl_xor(s1i, 16);
        }

        // ---- F norms (from regs) ----
        float s1, s2;
        {
            float m = fr*fr + fi*fi;
            #pragma unroll
            for (int s = 1; s < 16; s <<= 1) m += __shfl_xor(m, s);
            float other = __shfl_xor(m, 16);
            float nrm1 = selF ? other : m;
            float nrm2 = selF ? m : other;
            s1 = sqrtf(2.0f / nrm1);
            s2 = sqrtf(2.0f / nrm2);
        }

        // ---- A/C entries (F values from regs) ----
        {
            float2 phi1n = make_float2(ph.x, ph.y);
            float2 phi2n = make_float2(ph.z, ph.w);
            bool lo = (e8 < 4);
            float2 E0 = cmul(phi1n, lo ? f1 : f2);
            float2 E1 = cmul(phi2n, lo ? f2 : f1);
            #pragma unroll
            for (int s = 1; s < 8; s <<= 1) {
                E0.x += __shfl_xor(E0.x, s); E0.y += __shfl_xor(E0.y, s);
                E1.x += __shfl_xor(E1.x, s); E1.y += __shfl_xor(E1.y, s);
            }
            if (t == 0) {
                ent[wave][it][e8]     = cscale(lo ? s1 : s2, E0);
                ent[wave][it][e8 + 8] = cscale(lo ? s2 : s1, E1);
            }
        }
    }
    #undef STAGE
    #undef LDU2
    #undef JGROUP_PK
    asm volatile("s_waitcnt lgkmcnt(0)" ::: "memory");
    __builtin_amdgcn_wave_barrier();

    // ---- batched 2x2 complex rate: lanes 0..7 -> (it = lane>>1, R1/R2 = lane&1) ----
    float negR = 0.0f;
    if (lane < 8) {
        const float2* e = &ent[wave][lane >> 1][(lane & 1) * 8];
        float2 A00=e[0], A01=e[1], A10=e[2], A11=e[3];
        float2 C00=e[4], C01=e[5], C10=e[6], C11=e[7];
        float mu00 = C00.x*C00.x + C00.y*C00.y + C01.x*C01.x + C01.y*C01.y + NOISE;
        float mu11 = C10.x*C10.x + C10.y*C10.y + C11.x*C11.x + C11.y*C11.y + NOISE;
        float2 mu01 = cadd(cmulconj(C00, C10), cmulconj(C01, C11));
        mu01.x += NOISE;
        float det = mu00*mu11 - (mu01.x*mu01.x + mu01.y*mu01.y);
        float inv = 1.0f / det;
        float2 mu01c = make_float2(mu01.x, -mu01.y);
        float2 X00 = cscale(inv, csub(cscale(mu11, A00), cmul(mu01,  A10)));
        float2 X01 = cscale(inv, csub(cscale(mu11, A01), cmul(mu01,  A11)));
        float2 X10 = cscale(inv, csub(cscale(mu00, A10), cmul(mu01c, A00)));
        float2 X11 = cscale(inv, csub(cscale(mu00, A11), cmul(mu01c, A01)));
        float2 I00 = cadd(cconjmul(A00, X00), cconjmul(A10, X10));
        float2 I01 = cadd(cconjmul(A00, X01), cconjmul(A10, X11));
        float2 I10 = cadd(cconjmul(A01, X00), cconjmul(A11, X10));
        float2 I11 = cadd(cconjmul(A01, X01), cconjmul(A11, X11));
        I00.x += 1.0f; I01.x += 1.0f; I10.x += 1.0f; I11.x += 1.0f;
        float2 dT = csub(cmul(I00, I11), cmul(I01, I10));
        negR = -0.5f * logf(dT.x*dT.x + dT.y*dT.y);  // -Re(log z) = -ln|z|
    }
    // pairwise max over (R1,R2), then sum the 4 batch elements
    float m = fmaxf(negR, __shfl_xor(negR, 1));
    m += __shfl_xor(m, 2);
    m += __shfl_xor(m, 4);
    if (lane == 0) wsum[wave] = m;

    __syncthreads();
    if (threadIdx.x == 0)
        partial[blockIdx.x] = (wsum[0] + wsum[1]) + (wsum[2] + wsum[3]);
}

__global__ __launch_bounds__(256) void reduce_kernel(
    const float* __restrict__ partial, int n, float invB, float* __restrict__ out)
{
    __shared__ float sd[256];
    float s = 0.0f;
    for (int i = threadIdx.x; i < n; i += 256) s += partial[i];
    sd[threadIdx.x] = s;
    __syncthreads();
    for (int o = 128; o > 0; o >>= 1) {
        if ((int)threadIdx.x < o) sd[threadIdx.x] += sd[threadIdx.x + o];
        __syncthreads();
    }
    if (threadIdx.x == 0) out[0] = sd[0] * invB;
}

extern "C" void kernel_launch(void* const* d_in, const int* in_sizes, int n_in,
                              void* d_out, int out_size, void* d_ws, size_t ws_size,
                              hipStream_t stream) {
    const float* t1  = (const float*)d_in[0];
    const float* G1r = (const float*)d_in[1];
    const float* G1i = (const float*)d_in[2];
    const float* G2r = (const float*)d_in[3];
    const float* G2i = (const float*)d_in[4];
    const float* Ur  = (const float*)d_in[5];
    const float* Ui  = (const float*)d_in[6];

    const int B = in_sizes[0] / 264;        // 65536
    const int nblocks = B / 16;             // 16 batch elements per block
    float* partial = (float*)d_ws;          // nblocks floats

    rate_kernel<<<nblocks, 256, 0, stream>>>(t1, G1r, G1i, G2r, G2i, Ur, Ui, partial);
    reduce_kernel<<<1, 256, 0, stream>>>(partial, nblocks, 1.0f / (float)B, (float*)d_out);
}

// Round 15
// 135.003 us; speedup vs baseline: 1.0242x; 1.0242x over previous
//
#include <hip/hip_runtime.h>
#include <math.h>

#define NOISE 1e-12f
#define WSZ 1064    // floats per staging buffer: THc(200) | F(64) | G1c(400) | G2c(400)
#define WSZ4 266

typedef float f32x2 __attribute__((ext_vector_type(2)));

__device__ __forceinline__ f32x2 mk2(float x, float y){ f32x2 r; r.x = x; r.y = y; return r; }

// packed complex multiply: returns a (x) b, 2 VOP3P instructions
__device__ __forceinline__ f32x2 cmul_pk(f32x2 a, f32x2 b) {
    f32x2 w;
    asm("v_pk_mul_f32 %0, %1, %2 op_sel:[0,0] op_sel_hi:[0,1]\n\t"
        "v_pk_fma_f32 %0, %1, %2, %0 op_sel:[1,1,0] op_sel_hi:[1,0,1] neg_lo:[0,1,0]"
        : "=&v"(w) : "v"(a), "v"(b));
    return w;
}
// packed complex FMA: p += a (x) w, 2 VOP3P instructions
__device__ __forceinline__ void cfma_pk(f32x2& p, f32x2 a, f32x2 w) {
    asm("v_pk_fma_f32 %0, %1, %2, %0 op_sel:[0,0,0] op_sel_hi:[0,1,1]\n\t"
        "v_pk_fma_f32 %0, %1, %2, %0 op_sel:[1,1,0] op_sel_hi:[1,0,1] neg_lo:[0,1,0]"
        : "+v"(p) : "v"(a), "v"(w));
}

__device__ __forceinline__ float2 cmul(float2 a, float2 b) {
    return make_float2(a.x*b.x - a.y*b.y, a.x*b.y + a.y*b.x);
}
__device__ __forceinline__ float2 cconjmul(float2 a, float2 b) {
    return make_float2(a.x*b.x + a.y*b.y, a.x*b.y - a.y*b.x);
}
__device__ __forceinline__ float2 cmulconj(float2 a, float2 b) {
    return make_float2(a.x*b.x + a.y*b.y, a.y*b.x - a.x*b.y);
}
__device__ __forceinline__ float2 cadd(float2 a, float2 b){ return make_float2(a.x+b.x, a.y+b.y); }
__device__ __forceinline__ float2 csub(float2 a, float2 b){ return make_float2(a.x-b.x, a.y-b.y); }
__device__ __forceinline__ float2 cscale(float s, float2 a){ return make_float2(s*a.x, s*a.y); }

// async global->LDS, 4 B per lane: lane l writes dst+4*l from per-lane src.
typedef const void __attribute__((address_space(1)))* gas_t;
typedef void __attribute__((address_space(3)))* las_t;
__device__ __forceinline__ void gll4(const float* g, float* l) {
    __builtin_amdgcn_global_load_lds((gas_t)g, (las_t)l, 4, 0, 0);
}

// one wave per batch element iteration; 4 waves/block; 4 iterations -> 16 b per block
__global__ __launch_bounds__(256) void rate_kernel(
    const float* __restrict__ t1,
    const float* __restrict__ G1r, const float* __restrict__ G1i,
    const float* __restrict__ G2r, const float* __restrict__ G2i,
    const float* __restrict__ Ur,  const float* __restrict__ Ui,
    float* __restrict__ partial)
{
    __shared__ float4 lds4[4 * WSZ4];   // per-wave SINGLE staging buffer
    __shared__ float2 ent[4][4][16];    // [wave][it][entry]
    __shared__ float wsum[4];
    const int wave = threadIdx.x >> 6;
    const int lane = threadIdx.x & 63;
    const int t2 = lane & 3;       // t-pair index: t = 2*t2, 2*t2+1
    const int k0 = lane >> 2;      // k-strip (k = k0 + 16j), doubles as entry id e=k0
    float* W = (float*)(lds4 + wave * WSZ4);

    const int half  = lane & 1;
    const int qh    = lane >> 1;

    // LDS layout (floats): THc[0..199]=(θr,θi)x100 | F[200..263] raw tb[200..263] |
    //   G1c[264..663]=(g1r,g1i) rows n0,n1 | G2c[664..1063]
    #define STAGE(dst, bb) {                                                   \
        const float* tb_ = t1 + (long)(bb) * 264;                              \
        const float* ts  = tb_ + (half ? 100 : 0) + qh;                        \
        gll4(ts,       (dst));        gll4(ts + 32,  (dst) + 64);              \
        gll4(ts + 64,  (dst) + 128);                                           \
        if (lane < 8) gll4(ts + 96, (dst) + 192);                              \
        gll4(tb_ + 200 + lane, (dst) + 200);                                   \
        const float* g1 = (half ? G1i : G1r) + (long)(bb) * 200 + qh;          \
        const float* g2 = (half ? G2i : G2r) + (long)(bb) * 200 + qh;          \
        gll4(g1,        (dst)+264);   gll4(g1+32,  (dst)+328);                 \
        gll4(g1+64,     (dst)+392);   gll4(g1+96,  (dst)+456);                 \
        gll4(g1+128,    (dst)+520);   gll4(g1+160, (dst)+584);                 \
        if (lane < 16) gll4(g1+192, (dst)+648);                                \
        gll4(g2,        (dst)+664);   gll4(g2+32,  (dst)+728);                 \
        gll4(g2+64,     (dst)+792);   gll4(g2+96,  (dst)+856);                 \
        gll4(g2+128,    (dst)+920);   gll4(g2+160, (dst)+984);                 \
        if (lane < 16) gll4(g2+192, (dst)+1048);                               \
    }

    const long bbase = (long)blockIdx.x * 16 + (long)wave * 4;
    STAGE(W, bbase);   // prologue: stage b0 (19 issues)

    const float* urb = Ur + bbase * 800;
    const float* uib = Ui + bbase * 800;
    const int ubase = 8 * k0 + 2 * t2;                       // + 128*j per group
    const int utail = 8 * (96 + (k0 < 4 ? k0 : 3)) + 2 * t2; // clamped, in-bounds
    #define LD2(p, idx) (*(const float2*)((p) + (idx)))

    // initial U prefetch for it 0, groups j=0..3 (8 float2 loads, fully coalesced)
    float2 g0r = LD2(urb, ubase),       g0i = LD2(uib, ubase);
    float2 g1r = LD2(urb, ubase+128),   g1i = LD2(uib, ubase+128);
    float2 g2r = LD2(urb, ubase+256),   g2i = LD2(uib, ubase+256);
    float2 g3r = LD2(urb, ubase+384),   g3i = LD2(uib, ubase+384);

    // one j-group: 5 ds_read_b64 + 2 cmul_pk + 8 cfma_pk (20 VOP3P), 2 t's per lane
    #define JBODY(j, gr, gi) {                                        \
        const int kk = 2*k0 + 32*(j);                                 \
        f32x2 th = *(const f32x2*)(W + kk);                           \
        f32x2 ga = *(const f32x2*)(W + 264 + kk);                     \
        f32x2 gc = *(const f32x2*)(W + 464 + kk);                     \
        f32x2 gd = *(const f32x2*)(W + 664 + kk);                     \
        f32x2 ge = *(const f32x2*)(W + 864 + kk);                     \
        f32x2 w0 = cmul_pk(th, mk2((gr).x, (gi).x));                  \
        f32x2 w1 = cmul_pk(th, mk2((gr).y, (gi).y));                  \
        cfma_pk(p10a, ga, w0);  cfma_pk(p10b, ga, w1);                \
        cfma_pk(p11a, gc, w0);  cfma_pk(p11b, gc, w1);                \
        cfma_pk(p20a, gd, w0);  cfma_pk(p20b, gd, w1);                \
        cfma_pk(p21a, ge, w0);  cfma_pk(p21b, ge, w1); }

    const int idxF = lane & 15;
    const int selF = (lane >> 4) & 1;
    const bool useF1 = (k0 < 4) || (k0 >= 12);   // A1 and C2 use F1/s1
    const int fb = useF1 ? 200 : 232;
    const int i0 = 4*t2 + (k0 & 1);              // F' index 2*t0 + r

    #pragma unroll 1
    for (int it = 0; it < 4; ++it) {
        // outstanding = [19 stage (older)] + [8 U (newer)] -> drain the staging
        asm volatile("s_waitcnt vmcnt(8)" ::: "memory");
        __builtin_amdgcn_sched_barrier(0);

        // pull F scalars into regs (buffer is overwritten mid-it)
        float fr = W[200 + selF*32 + idxF];
        float fi = W[216 + selF*32 + idxF];
        float2 fv0 = make_float2(W[fb + i0],     W[fb + 16 + i0]);
        float2 fv1 = make_float2(W[fb + i0 + 2], W[fb + 18 + i0]);

        // phi accumulators: [phi1 n0/n1, phi2 n0/n1] x [t0, t1], packed (re,im)
        f32x2 p10a=mk2(0,0), p10b=mk2(0,0), p11a=mk2(0,0), p11b=mk2(0,0);
        f32x2 p20a=mk2(0,0), p20b=mk2(0,0), p21a=mk2(0,0), p21b=mk2(0,0);

        // groups j=0..5 (k = k0+16j <= 95), in-loop prefetch of j=4,5,tail
        float2 g4r = LD2(urb, ubase+512), g4i = LD2(uib, ubase+512);
        JBODY(0, g0r, g0i);
        float2 g5r = LD2(urb, ubase+640), g5i = LD2(uib, ubase+640);
        JBODY(1, g1r, g1i);
        float2 g6r = LD2(urb, utail),     g6i = LD2(uib, utail);
        JBODY(2, g2r, g2i);
        JBODY(3, g3r, g3i);
        JBODY(4, g4r, g4i);
        JBODY(5, g5r, g5i);
        if (k0 < 4) JBODY(6, g6r, g6i);   // tail k = 96..99

        // restage same buffer for it+1 (gll4s fly under the shuffle phase),
        // then cross-it U prefetch (order keeps vmcnt split [19][8])
        if (it < 3) {
            asm volatile("s_waitcnt lgkmcnt(0)" ::: "memory");
            __builtin_amdgcn_sched_barrier(0);
            STAGE(W, bbase + it + 1);
            __builtin_amdgcn_sched_barrier(0);
            urb += 800; uib += 800;
            g0r = LD2(urb, ubase);     g0i = LD2(uib, ubase);
            g1r = LD2(urb, ubase+128); g1i = LD2(uib, ubase+128);
            g2r = LD2(urb, ubase+256); g2i = LD2(uib, ubase+256);
            g3r = LD2(urb, ubase+384); g3i = LD2(uib, ubase+384);
            __builtin_amdgcn_sched_barrier(0);
        }

        // ---- k-reduce over 16 strips (lane bits 2..5) ----
        float q[16] = {p10a.x,p10a.y,p10b.x,p10b.y,
                       p11a.x,p11a.y,p11b.x,p11b.y,
                       p20a.x,p20a.y,p20b.x,p20b.y,
                       p21a.x,p21a.y,p21b.x,p21b.y};
        #pragma unroll
        for (int i = 0; i < 16; ++i) q[i] += __shfl_xor(q[i], 4);
        // bit 3 = n-select: keep the n this lane's entry needs, send the other
        const int nsel = (lane >> 3) & 1;
        float r8[8];
        #pragma unroll
        for (int i = 0; i < 4; ++i) {
            float ka = nsel ? q[4+i]  : q[i];
            float sa = nsel ? q[i]    : q[4+i];
            r8[i]   = ka + __shfl_xor(sa, 8);
            float kb = nsel ? q[12+i] : q[8+i];
            float sb = nsel ? q[8+i]  : q[12+i];
            r8[4+i] = kb + __shfl_xor(sb, 8);
        }
        #pragma unroll
        for (int i = 0; i < 8; ++i) r8[i] += __shfl_xor(r8[i], 16);
        // bit 5 = phi1/phi2 select (entry e=k0: e<8 -> phi1)
        const int msel = (lane >> 5) & 1;
        float ph[4];
        #pragma unroll
        for (int i = 0; i < 4; ++i) {
            float kp = msel ? r8[4+i] : r8[i];
            float sp = msel ? r8[i]   : r8[4+i];
            ph[i] = kp + __shfl_xor(sp, 32);
        }
        // ph = {t0.re, t0.im, t1.re, t1.im} of phi_{m'}[n], fully k-summed

        // ---- F norms (from regs) ----
        float m = fr*fr + fi*fi;
        #pragma unroll
        for (int s = 1; s < 16; s <<= 1) m += __shfl_xor(m, s);
        float other = __shfl_xor(m, 16);
        float nrm1 = selF ? other : m;
        float nrm2 = selF ? m : other;
        float sc1 = sqrtf(2.0f / nrm1);
        float sc2 = sqrtf(2.0f / nrm2);
        float sE = useF1 ? sc1 : sc2;

        // ---- entry e = k0: partial over this lane's 2 t's, reduce over t2 ----
        float2 E = cadd(cmul(make_float2(ph[0], ph[1]), fv0),
                        cmul(make_float2(ph[2], ph[3]), fv1));
        E.x += __shfl_xor(E.x, 1); E.y += __shfl_xor(E.y, 1);
        E.x += __shfl_xor(E.x, 2); E.y += __shfl_xor(E.y, 2);
        if (t2 == 0) ent[wave][it][k0] = cscale(sE, E);
    }
    #undef STAGE
    #undef LD2
    #undef JBODY
    asm volatile("s_waitcnt lgkmcnt(0)" ::: "memory");
    __builtin_amdgcn_wave_barrier();

    // ---- batched 2x2 complex rate: lanes 0..7 -> (it = lane>>1, R1/R2 = lane&1) ----
    float negR = 0.0f;
    if (lane < 8) {
        const float2* e = &ent[wave][lane >> 1][(lane & 1) * 8];
        float2 A00=e[0], A01=e[1], A10=e[2], A11=e[3];
        float2 C00=e[4], C01=e[5], C10=e[6], C11=e[7];
        float mu00 = C00.x*C00.x + C00.y*C00.y + C01.x*C01.x + C01.y*C01.y + NOISE;
        float mu11 = C10.x*C10.x + C10.y*C10.y + C11.x*C11.x + C11.y*C11.y + NOISE;
        float2 mu01 = cadd(cmulconj(C00, C10), cmulconj(C01, C11));
        mu01.x += NOISE;
        float det = mu00*mu11 - (mu01.x*mu01.x + mu01.y*mu01.y);
        float inv = 1.0f / det;
        float2 mu01c = make_float2(mu01.x, -mu01.y);
        float2 X00 = cscale(inv, csub(cscale(mu11, A00), cmul(mu01,  A10)));
        float2 X01 = cscale(inv, csub(cscale(mu11, A01), cmul(mu01,  A11)));
        float2 X10 = cscale(inv, csub(cscale(mu00, A10), cmul(mu01c, A00)));
        float2 X11 = cscale(inv, csub(cscale(mu00, A11), cmul(mu01c, A01)));
        float2 I00 = cadd(cconjmul(A00, X00), cconjmul(A10, X10));
        float2 I01 = cadd(cconjmul(A00, X01), cconjmul(A10, X11));
        float2 I10 = cadd(cconjmul(A01, X00), cconjmul(A11, X10));
        float2 I11 = cadd(cconjmul(A01, X01), cconjmul(A11, X11));
        I00.x += 1.0f; I01.x += 1.0f; I10.x += 1.0f; I11.x += 1.0f;
        float2 dT = csub(cmul(I00, I11), cmul(I01, I10));
        negR = -0.5f * logf(dT.x*dT.x + dT.y*dT.y);  // -Re(log z) = -ln|z|
    }
    // pairwise max over (R1,R2), then sum the 4 batch elements
    float m = fmaxf(negR, __shfl_xor(negR, 1));
    m += __shfl_xor(m, 2);
    m += __shfl_xor(m, 4);
    if (lane == 0) wsum[wave] = m;

    __syncthreads();
    if (threadIdx.x == 0)
        partial[blockIdx.x] = (wsum[0] + wsum[1]) + (wsum[2] + wsum[3]);
}

__global__ __launch_bounds__(256) void reduce_kernel(
    const float* __restrict__ partial, int n, float invB, float* __restrict__ out)
{
    __shared__ float sd[256];
    float s = 0.0f;
    for (int i = threadIdx.x; i < n; i += 256) s += partial[i];
    sd[threadIdx.x] = s;
    __syncthreads();
    for (int o = 128; o > 0; o >>= 1) {
        if ((int)threadIdx.x < o) sd[threadIdx.x] += sd[threadIdx.x + o];
        __syncthreads();
    }
    if (threadIdx.x == 0) out[0] = sd[0] * invB;
}

extern "C" void kernel_launch(void* const* d_in, const int* in_sizes, int n_in,
                              void* d_out, int out_size, void* d_ws, size_t ws_size,
                              hipStream_t stream) {
    const float* t1  = (const float*)d_in[0];
    const float* G1r = (const float*)d_in[1];
    const float* G1i = (const float*)d_in[2];
    const float* G2r = (const float*)d_in[3];
    const float* G2i = (const float*)d_in[4];
    const float* Ur  = (const float*)d_in[5];
    const float* Ui  = (const float*)d_in[6];

    const int B = in_sizes[0] / 264;        // 65536
    const int nblocks = B / 16;             // 16 batch elements per block
    float* partial = (float*)d_ws;          // nblocks floats

    rate_kernel<<<nblocks, 256, 0, stream>>>(t1, G1r, G1i, G2r, G2i, Ur, Ui, partial);
    reduce_kernel<<<1, 256, 0, stream>>>(partial, nblocks, 1.0f / (float)B, (float*)d_out);
}

// Round 16
// 134.308 us; speedup vs baseline: 1.0294x; 1.0052x over previous
//
#include <hip/hip_runtime.h>
#include <math.h>

#define NOISE 1e-12f
#define WSZ 1064    // floats per staging buffer: T(264) | G1r(200) | G1i(200) | G2r(200) | G2i(200)
#define WSZ4 266

typedef float f32x2 __attribute__((ext_vector_type(2)));

__device__ __forceinline__ f32x2 mk2(float x, float y){ f32x2 r; r.x = x; r.y = y; return r; }

// packed complex multiply: returns a (x) b, 2 VOP3P instructions
__device__ __forceinline__ f32x2 cmul_pk(f32x2 a, f32x2 b) {
    f32x2 w;
    asm("v_pk_mul_f32 %0, %1, %2 op_sel:[0,0] op_sel_hi:[0,1]\n\t"
        "v_pk_fma_f32 %0, %1, %2, %0 op_sel:[1,1,0] op_sel_hi:[1,0,1] neg_lo:[0,1,0]"
        : "=&v"(w) : "v"(a), "v"(b));
    return w;
}
// packed complex FMA: p += a (x) w, 2 VOP3P instructions
__device__ __forceinline__ void cfma_pk(f32x2& p, f32x2 a, f32x2 w) {
    asm("v_pk_fma_f32 %0, %1, %2, %0 op_sel:[0,0,0] op_sel_hi:[0,1,1]\n\t"
        "v_pk_fma_f32 %0, %1, %2, %0 op_sel:[1,1,0] op_sel_hi:[1,0,1] neg_lo:[0,1,0]"
        : "+v"(p) : "v"(a), "v"(w));
}

__device__ __forceinline__ float2 cmul(float2 a, float2 b) {
    return make_float2(a.x*b.x - a.y*b.y, a.x*b.y + a.y*b.x);
}
__device__ __forceinline__ float2 cconjmul(float2 a, float2 b) {
    return make_float2(a.x*b.x + a.y*b.y, a.x*b.y - a.y*b.x);
}
__device__ __forceinline__ float2 cmulconj(float2 a, float2 b) {
    return make_float2(a.x*b.x + a.y*b.y, a.y*b.x - a.x*b.y);
}
__device__ __forceinline__ float2 cadd(float2 a, float2 b){ return make_float2(a.x+b.x, a.y+b.y); }
__device__ __forceinline__ float2 csub(float2 a, float2 b){ return make_float2(a.x-b.x, a.y-b.y); }
__device__ __forceinline__ float2 cscale(float s, float2 a){ return make_float2(s*a.x, s*a.y); }

// async global->LDS, 16 B per lane (fire-and-forget; counted by vmcnt)
typedef const void __attribute__((address_space(1)))* gas_t;
typedef void __attribute__((address_space(3)))* las_t;
__device__ __forceinline__ void gll16(const float* g, float* l) {
    __builtin_amdgcn_global_load_lds((gas_t)g, (las_t)l, 16, 0, 0);
}

// one wave per batch element iteration; 4 waves/block; 4 iterations -> 16 b per block
__global__ __launch_bounds__(256) void rate_kernel(
    const float* __restrict__ t1,
    const float* __restrict__ G1r, const float* __restrict__ G1i,
    const float* __restrict__ G2r, const float* __restrict__ G2i,
    const float* __restrict__ Ur,  const float* __restrict__ Ui,
    float* __restrict__ partial)
{
    __shared__ float4 lds4[4 * WSZ4];   // per-wave SINGLE staging buffer (linear)
    __shared__ float2 ent[4][4][16];    // [wave][it][entry]
    __shared__ float wsum[4];
    const int wave = threadIdx.x >> 6;
    const int lane = threadIdx.x & 63;
    const int h  = lane & 1;       // t-half: lane owns t = 4h..4h+3
    const int k0 = lane >> 1;      // k-strip (k = k0 + 32j), 32 strips
    float* W = (float*)(lds4 + wave * WSZ4);

    // linear STAGE: 6 gll16 issues (dwordx4 path, minimal TA addresses)
    #define STAGE(dst, bb) {                                                   \
        const float* tb_ = t1 + (long)(bb) * 264;                              \
        gll16(tb_ + lane * 4, (dst));                                          \
        if (lane < 2)  gll16(tb_ + 256 + lane * 4, (dst) + 256);               \
        if (lane < 50) {                                                       \
            gll16(G1r + (long)(bb) * 200 + lane * 4, (dst) + 264);             \
            gll16(G1i + (long)(bb) * 200 + lane * 4, (dst) + 464);             \
            gll16(G2r + (long)(bb) * 200 + lane * 4, (dst) + 664);             \
            gll16(G2i + (long)(bb) * 200 + lane * 4, (dst) + 864);             \
        }                                                                      \
    }

    const long bbase = (long)blockIdx.x * 16 + (long)wave * 4;
    STAGE(W, bbase);   // prologue

    const float* urb = Ur + bbase * 800;
    const float* uib = Ui + bbase * 800;
    const int ubase = 8 * k0 + 4 * h;                       // float4 base; +256 per j
    const int utail = 768 + 8 * (k0 < 4 ? k0 : 3) + 4 * h;  // clamped, in-bounds
    #define LD4(p, idx) (*(const float4*)((p) + (idx)))

    // initial U prefetch for it 0, j=0,1
    float4 u0r = LD4(urb, ubase),     u0i = LD4(uib, ubase);
    float4 u1r = LD4(urb, ubase+256), u1i = LD4(uib, ubase+256);

    // one j-strip: 5 paired DS reads + 4 cmul_pk + 16 cfma_pk
    #define JBODY(kk, ur4, ui4) {                                     \
        f32x2 th = mk2(W[(kk)],     W[100+(kk)]);                     \
        f32x2 ga = mk2(W[264+(kk)], W[464+(kk)]);                     \
        f32x2 gc = mk2(W[364+(kk)], W[564+(kk)]);                     \
        f32x2 gd = mk2(W[664+(kk)], W[864+(kk)]);                     \
        f32x2 ge = mk2(W[764+(kk)], W[964+(kk)]);                     \
        f32x2 w0 = cmul_pk(th, mk2((ur4).x,(ui4).x));                 \
        f32x2 w1 = cmul_pk(th, mk2((ur4).y,(ui4).y));                 \
        f32x2 w2 = cmul_pk(th, mk2((ur4).z,(ui4).z));                 \
        f32x2 w3 = cmul_pk(th, mk2((ur4).w,(ui4).w));                 \
        cfma_pk(pa0,ga,w0); cfma_pk(pa1,ga,w1); cfma_pk(pa2,ga,w2); cfma_pk(pa3,ga,w3); \
        cfma_pk(pb0,gc,w0); cfma_pk(pb1,gc,w1); cfma_pk(pb2,gc,w2); cfma_pk(pb3,gc,w3); \
        cfma_pk(pc0,gd,w0); cfma_pk(pc1,gd,w1); cfma_pk(pc2,gd,w2); cfma_pk(pc3,gd,w3); \
        cfma_pk(pd0,ge,w0); cfma_pk(pd1,ge,w1); cfma_pk(pd2,ge,w2); cfma_pk(pd3,ge,w3); }

    // entry id e = lane>>2: e0=r(bit2), e1=n(bit3), e2=A/C(bit4), e3=rate m(bit5)
    const int idxF = lane & 15;
    const int selF = (lane >> 4) & 1;
    const int rF   = (lane >> 2) & 1;
    const bool useF1 = (((lane >> 4) & 1) == ((lane >> 5) & 1));  // A1,C2 use F1
    const int fb = useF1 ? 200 : 232;
    const int fi0 = 8 * h + rF;          // f index 2t+r at t=4h+i: fi0 + 2i

    #pragma unroll 1
    for (int it = 0; it < 4; ++it) {
        // outstanding = [6 stage (older)] + [4 U (newer)] -> drain the staging
        asm volatile("s_waitcnt vmcnt(4)" ::: "memory");
        __builtin_amdgcn_sched_barrier(0);

        // pull F scalars into regs (buffer is overwritten mid-it)
        float fnr = W[200 + selF*32 + idxF];
        float fni = W[216 + selF*32 + idxF];
        float2 fv0 = make_float2(W[fb + fi0],     W[fb + 16 + fi0]);
        float2 fv1 = make_float2(W[fb + fi0 + 2], W[fb + 18 + fi0]);
        float2 fv2 = make_float2(W[fb + fi0 + 4], W[fb + 20 + fi0]);
        float2 fv3 = make_float2(W[fb + fi0 + 6], W[fb + 22 + fi0]);

        // accumulators: pa=phi1 n0, pb=phi1 n1, pc=phi2 n0, pd=phi2 n1 (t0..t3)
        f32x2 pa0=mk2(0,0),pa1=mk2(0,0),pa2=mk2(0,0),pa3=mk2(0,0);
        f32x2 pb0=mk2(0,0),pb1=mk2(0,0),pb2=mk2(0,0),pb3=mk2(0,0);
        f32x2 pc0=mk2(0,0),pc1=mk2(0,0),pc2=mk2(0,0),pc3=mk2(0,0);
        f32x2 pd0=mk2(0,0),pd1=mk2(0,0),pd2=mk2(0,0),pd3=mk2(0,0);

        // j-strips with in-body prefetch of j=2 and tail
        float4 u2r = LD4(urb, ubase+512), u2i = LD4(uib, ubase+512);
        JBODY(k0, u0r, u0i);
        float4 utr = LD4(urb, utail),     uti = LD4(uib, utail);
        JBODY(k0+32, u1r, u1i);
        JBODY(k0+64, u2r, u2i);
        if (k0 < 4) JBODY(k0+96, utr, uti);

        // restage same buffer for it+1 (gll16s fly under the shuffle phase),
        // then next it's U prefetch (order keeps the vmcnt split [6][4])
        if (it < 3) {
            asm volatile("s_waitcnt lgkmcnt(0)" ::: "memory");
            __builtin_amdgcn_sched_barrier(0);
            STAGE(W, bbase + it + 1);
            __builtin_amdgcn_sched_barrier(0);
            urb += 800; uib += 800;
            u0r = LD4(urb, ubase);     u0i = LD4(uib, ubase);
            u1r = LD4(urb, ubase+256); u1i = LD4(uib, ubase+256);
            __builtin_amdgcn_sched_barrier(0);
        }

        // ---- k-reduce over 32 strips (lane bits 1..5) ----
        float q[32] = {pa0.x,pa0.y,pa1.x,pa1.y,pa2.x,pa2.y,pa3.x,pa3.y,
                       pb0.x,pb0.y,pb1.x,pb1.y,pb2.x,pb2.y,pb3.x,pb3.y,
                       pc0.x,pc0.y,pc1.x,pc1.y,pc2.x,pc2.y,pc3.x,pc3.y,
                       pd0.x,pd0.y,pd1.x,pd1.y,pd2.x,pd2.y,pd3.x,pd3.y};
        // xor32: rate-select (keep phi_{1+msel}), keep/send exchange
        const int msel = (lane >> 5) & 1;
        float r16[16];
        #pragma unroll
        for (int i = 0; i < 16; ++i) {
            float ka = msel ? q[16+i] : q[i];
            float sa = msel ? q[i]    : q[16+i];
            r16[i] = ka + __shfl_xor(sa, 32);
        }
        // xor16: plain
        #pragma unroll
        for (int i = 0; i < 16; ++i) r16[i] += __shfl_xor(r16[i], 16);
        // xor8: n-select, keep/send
        const int nsel = (lane >> 3) & 1;
        float r8[8];
        #pragma unroll
        for (int i = 0; i < 8; ++i) {
            float ka = nsel ? r16[8+i] : r16[i];
            float sa = nsel ? r16[i]   : r16[8+i];
            r8[i] = ka + __shfl_xor(sa, 8);
        }
        // xor4, xor2: plain
        #pragma unroll
        for (int i = 0; i < 8; ++i) {
            r8[i] += __shfl_xor(r8[i], 4);
            r8[i] += __shfl_xor(r8[i], 2);
        }
        // r8 = phi_m[n][t=4h+i] (re,im) pairs, fully k-summed

        // ---- F norms (from regs) ----
        float m = fnr*fnr + fni*fni;
        #pragma unroll
        for (int s = 1; s < 16; s <<= 1) m += __shfl_xor(m, s);
        float other = __shfl_xor(m, 16);
        float nrm1 = selF ? other : m;
        float nrm2 = selF ? m : other;
        float sc1 = sqrtf(2.0f / nrm1);
        float sc2 = sqrtf(2.0f / nrm2);
        float sE = useF1 ? sc1 : sc2;

        // ---- entry e = lane>>2: partial over this lane's 4 t's, reduce over h ----
        float2 E = cadd(cadd(cmul(make_float2(r8[0],r8[1]), fv0),
                             cmul(make_float2(r8[2],r8[3]), fv1)),
                        cadd(cmul(make_float2(r8[4],r8[5]), fv2),
                             cmul(make_float2(r8[6],r8[7]), fv3)));
        E.x += __shfl_xor(E.x, 1); E.y += __shfl_xor(E.y, 1);
        if ((lane & 3) == 0) ent[wave][it][lane >> 2] = cscale(sE, E);
    }
    #undef STAGE
    #undef LD4
    #undef JBODY
    asm volatile("s_waitcnt lgkmcnt(0)" ::: "memory");
    __builtin_amdgcn_wave_barrier();

    // ---- batched 2x2 complex rate: lanes 0..7 -> (it = lane>>1, R1/R2 = lane&1) ----
    float negR = 0.0f;
    if (lane < 8) {
        const float2* e = &ent[wave][lane >> 1][(lane & 1) * 8];
        float2 A00=e[0], A01=e[1], A10=e[2], A11=e[3];
        float2 C00=e[4], C01=e[5], C10=e[6], C11=e[7];
        float mu00 = C00.x*C00.x + C00.y*C00.y + C01.x*C01.x + C01.y*C01.y + NOISE;
        float mu11 = C10.x*C10.x + C10.y*C10.y + C11.x*C11.x + C11.y*C11.y + NOISE;
        float2 mu01 = cadd(cmulconj(C00, C10), cmulconj(C01, C11));
        mu01.x += NOISE;
        float det = mu00*mu11 - (mu01.x*mu01.x + mu01.y*mu01.y);
        float inv = 1.0f / det;
        float2 mu01c = make_float2(mu01.x, -mu01.y);
        float2 X00 = cscale(inv, csub(cscale(mu11, A00), cmul(mu01,  A10)));
        float2 X01 = cscale(inv, csub(cscale(mu11, A01), cmul(mu01,  A11)));
        float2 X10 = cscale(inv, csub(cscale(mu00, A10), cmul(mu01c, A00)));
        float2 X11 = cscale(inv, csub(cscale(mu00, A11), cmul(mu01c, A01)));
        float2 I00 = cadd(cconjmul(A00, X00), cconjmul(A10, X10));
        float2 I01 = cadd(cconjmul(A00, X01), cconjmul(A10, X11));
        float2 I10 = cadd(cconjmul(A01, X00), cconjmul(A11, X10));
        float2 I11 = cadd(cconjmul(A01, X01), cconjmul(A11, X11));
        I00.x += 1.0f; I01.x += 1.0f; I10.x += 1.0f; I11.x += 1.0f;
        float2 dT = csub(cmul(I00, I11), cmul(I01, I10));
        negR = -0.5f * logf(dT.x*dT.x + dT.y*dT.y);  // -Re(log z) = -ln|z|
    }
    // pairwise max over (R1,R2), then sum the 4 batch elements
    float m = fmaxf(negR, __shfl_xor(negR, 1));
    m += __shfl_xor(m, 2);
    m += __shfl_xor(m, 4);
    if (lane == 0) wsum[wave] = m;

    __syncthreads();
    if (threadIdx.x == 0)
        partial[blockIdx.x] = (wsum[0] + wsum[1]) + (wsum[2] + wsum[3]);
}

__global__ __launch_bounds__(256) void reduce_kernel(
    const float* __restrict__ partial, int n, float invB, float* __restrict__ out)
{
    __shared__ float sd[256];
    float s = 0.0f;
    for (int i = threadIdx.x; i < n; i += 256) s += partial[i];
    sd[threadIdx.x] = s;
    __syncthreads();
    for (int o = 128; o > 0; o >>= 1) {
        if ((int)threadIdx.x < o) sd[threadIdx.x] += sd[threadIdx.x + o];
        __syncthreads();
    }
    if (threadIdx.x == 0) out[0] = sd[0] * invB;
}

extern "C" void kernel_launch(void* const* d_in, const int* in_sizes, int n_in,
                              void* d_out, int out_size, void* d_ws, size_t ws_size,
                              hipStream_t stream) {
    const float* t1  = (const float*)d_in[0];
    const float* G1r = (const float*)d_in[1];
    const float* G1i = (const float*)d_in[2];
    const float* G2r = (const float*)d_in[3];
    const float* G2i = (const float*)d_in[4];
    const float* Ur  = (const float*)d_in[5];
    const float* Ui  = (const float*)d_in[6];

    const int B = in_sizes[0] / 264;        // 65536
    const int nblocks = B / 16;             // 16 batch elements per block
    float* partial = (float*)d_ws;          // nblocks floats

    rate_kernel<<<nblocks, 256, 0, stream>>>(t1, G1r, G1i, G2r, G2i, Ur, Ui, partial);
    reduce_kernel<<<1, 256, 0, stream>>>(partial, nblocks, 1.0f / (float)B, (float*)d_out);
}